// Round 16
// baseline (170.340 us; speedup 1.0000x reference)
//
#include <hip/hip_runtime.h>
#include <cstdint>

#define TS 8192      // tokens (S)
#define TD 4096      // model dim (D)
#define TE 64        // experts (E)
#define TCAP 128     // capacity
#define KS 16        // K-splits
#define KB (TD/KS)   // 256 k per block
#define KC 32        // k-chunk staged in LDS
#define TB 256       // tokens per block
#define NTB (TS/TB)  // 32 token-blocks

static constexpr size_t SEC = (size_t)TS * TE * TCAP;  // 67,108,864

typedef float f32x4 __attribute__((ext_vector_type(4)));

// ---------------------------------------------------------------------------
// Kernel A: block-role fused GEMM + fill, bid-PARITY interleaved.
// VGPR (~128) limits residency to 2 blocks/CU = 512 resident blocks. In R12
// (GEMM = bids 0..511) the fill blocks queued BEHIND the GEMM -> secretly
// serial. Parity mapping (even bid<1024 = GEMM, odd + >=1024 = fill) makes
// ~256 GEMM + ~256 fill co-resident from t=0: the 537 MB write stream
// overlaps the GEMM's read/compute, and fill churn back-fills GEMM density.
//  - GEMM role: R12 geometry verbatim (KS=16, TB=256, 8tok x 4exp,
//    reg-prefetch), ZERO fill quota (G(q) insensitivity: quota moves out).
//  - fill role: 1024 blocks x 32768 vecs (512 KB contiguous), NT stores,
//    no LDS / no barriers.
// ---------------------------------------------------------------------------
__global__ __launch_bounds__(512, 4) void gemm_fill_fused(
    const float* __restrict__ x, const float* __restrict__ wg,
    float* __restrict__ part, f32x4* __restrict__ out4,
    float* __restrict__ out)
{
    __shared__ float xs[KC][260];   // [k][token]
    __shared__ float wsh[KC][68];   // [k][expert]

    const int tid = threadIdx.x;
    const int bid = blockIdx.x;
    const f32x4 z4 = {0.f, 0.f, 0.f, 0.f};

    const bool is_gemm = (bid < 1024) && ((bid & 1) == 0);
    if (!is_gemm) {
        // ---------------- fill role: decoupled pure-write blocks ----------
        const int fid = (bid < 1024) ? (bid >> 1) : (512 + (bid - 1024));
        const long base = (long)fid * 32768;
        #pragma unroll
        for (int j = 0; j < 64; ++j)
            __builtin_nontemporal_store(z4, &out4[base + (long)j * 512 + tid]);
        if (fid == 0 && tid < 65) out[2 * SEC + tid] = 0.f;  // tail floats
        return;
    }

    // ---------------- GEMM role (R12 geometry, zero fill quota) -----------
    const int gid = bid >> 1;       // 0..511
    const int tb  = gid & (NTB - 1);
    const int ks  = gid >> 5;       // 0..15
    const int tok0 = tb * TB;
    const int tx = tid & 15;        // experts tx*4..+3
    const int ty = tid >> 4;        // tokens ty*8..+7
    const int kq_s  = tid & 7;
    const int row_s = tid >> 3;

    float acc[8][4];
    #pragma unroll
    for (int i = 0; i < 8; ++i)
        #pragma unroll
        for (int j = 0; j < 4; ++j) acc[i][j] = 0.f;

    // prefetch iteration 0 into registers
    f32x4 rx[4], rw;
    {
        const int k0 = ks * KB;
        #pragma unroll
        for (int r = 0; r < 4; ++r)
            rx[r] = __builtin_nontemporal_load(reinterpret_cast<const f32x4*>(
                &x[(size_t)(tok0 + r * 64 + row_s) * TD + k0 + kq_s * 4]));
        rw = *reinterpret_cast<const f32x4*>(&wg[(size_t)row_s * TD + k0 + kq_s * 4]);
    }

    for (int it = 0; it < KB / KC; ++it) {   // 8 iterations
        // commit staged registers to LDS (transposed)
        #pragma unroll
        for (int r = 0; r < 4; ++r) {
            const int t = r * 64 + row_s;
            xs[kq_s*4+0][t] = rx[r].x; xs[kq_s*4+1][t] = rx[r].y;
            xs[kq_s*4+2][t] = rx[r].z; xs[kq_s*4+3][t] = rx[r].w;
        }
        wsh[kq_s*4+0][row_s] = rw.x; wsh[kq_s*4+1][row_s] = rw.y;
        wsh[kq_s*4+2][row_s] = rw.z; wsh[kq_s*4+3][row_s] = rw.w;
        __syncthreads();
        // prefetch next iteration (drained during FMA section)
        if (it + 1 < KB / KC) {
            const int k0 = ks * KB + (it + 1) * KC;
            #pragma unroll
            for (int r = 0; r < 4; ++r)
                rx[r] = __builtin_nontemporal_load(reinterpret_cast<const f32x4*>(
                    &x[(size_t)(tok0 + r * 64 + row_s) * TD + k0 + kq_s * 4]));
            rw = *reinterpret_cast<const f32x4*>(&wg[(size_t)row_s * TD + k0 + kq_s * 4]);
        }
        // FMA section: 8 tok x 4 exp (no fill stores)
        #pragma unroll
        for (int k = 0; k < KC; ++k) {
            const f32x4 a0 = *reinterpret_cast<const f32x4*>(&xs[k][ty * 8]);
            const f32x4 a1 = *reinterpret_cast<const f32x4*>(&xs[k][ty * 8 + 4]);
            const f32x4 b  = *reinterpret_cast<const f32x4*>(&wsh[k][tx * 4]);
            acc[0][0] = fmaf(a0.x, b.x, acc[0][0]);
            acc[0][1] = fmaf(a0.x, b.y, acc[0][1]);
            acc[0][2] = fmaf(a0.x, b.z, acc[0][2]);
            acc[0][3] = fmaf(a0.x, b.w, acc[0][3]);
            acc[1][0] = fmaf(a0.y, b.x, acc[1][0]);
            acc[1][1] = fmaf(a0.y, b.y, acc[1][1]);
            acc[1][2] = fmaf(a0.y, b.z, acc[1][2]);
            acc[1][3] = fmaf(a0.y, b.w, acc[1][3]);
            acc[2][0] = fmaf(a0.z, b.x, acc[2][0]);
            acc[2][1] = fmaf(a0.z, b.y, acc[2][1]);
            acc[2][2] = fmaf(a0.z, b.z, acc[2][2]);
            acc[2][3] = fmaf(a0.z, b.w, acc[2][3]);
            acc[3][0] = fmaf(a0.w, b.x, acc[3][0]);
            acc[3][1] = fmaf(a0.w, b.y, acc[3][1]);
            acc[3][2] = fmaf(a0.w, b.z, acc[3][2]);
            acc[3][3] = fmaf(a0.w, b.w, acc[3][3]);
            acc[4][0] = fmaf(a1.x, b.x, acc[4][0]);
            acc[4][1] = fmaf(a1.x, b.y, acc[4][1]);
            acc[4][2] = fmaf(a1.x, b.z, acc[4][2]);
            acc[4][3] = fmaf(a1.x, b.w, acc[4][3]);
            acc[5][0] = fmaf(a1.y, b.x, acc[5][0]);
            acc[5][1] = fmaf(a1.y, b.y, acc[5][1]);
            acc[5][2] = fmaf(a1.y, b.z, acc[5][2]);
            acc[5][3] = fmaf(a1.y, b.w, acc[5][3]);
            acc[6][0] = fmaf(a1.z, b.x, acc[6][0]);
            acc[6][1] = fmaf(a1.z, b.y, acc[6][1]);
            acc[6][2] = fmaf(a1.z, b.z, acc[6][2]);
            acc[6][3] = fmaf(a1.z, b.w, acc[6][3]);
            acc[7][0] = fmaf(a1.w, b.x, acc[7][0]);
            acc[7][1] = fmaf(a1.w, b.y, acc[7][1]);
            acc[7][2] = fmaf(a1.w, b.z, acc[7][2]);
            acc[7][3] = fmaf(a1.w, b.w, acc[7][3]);
        }
        __syncthreads();
    }
    // write partial logits: part[ks][tok][exp]
    #pragma unroll
    for (int i = 0; i < 8; ++i) {
        const int t = tok0 + ty * 8 + i;
        f32x4 v;
        v.x = acc[i][0]; v.y = acc[i][1]; v.z = acc[i][2]; v.w = acc[i][3];
        *reinterpret_cast<f32x4*>(&part[((size_t)ks * TS + t) * TE + tx * 4]) = v;
    }
}

// ---------------------------------------------------------------------------
// Kernel B: reduce K-split partials + softmax + argmax per token.
// ---------------------------------------------------------------------------
__global__ __launch_bounds__(256) void softmax_argmax(
    const float* __restrict__ part, int* __restrict__ eidx,
    float* __restrict__ gtop, float* __restrict__ partial_me)
{
    __shared__ float cs[4][64];
    const int tid = threadIdx.x;
    const int tx = tid & 15;
    const int ty = tid >> 4;
    const int s = blockIdx.x * 16 + ty;

    float p[4] = {0.f, 0.f, 0.f, 0.f};
    #pragma unroll
    for (int ks = 0; ks < KS; ++ks) {
        const f32x4 v = *reinterpret_cast<const f32x4*>(
            &part[((size_t)ks * TS + s) * TE + tx * 4]);
        p[0] += v.x; p[1] += v.y; p[2] += v.z; p[3] += v.w;
    }

    float lm = fmaxf(fmaxf(p[0], p[1]), fmaxf(p[2], p[3]));
    #pragma unroll
    for (int mask = 1; mask <= 8; mask <<= 1)
        lm = fmaxf(lm, __shfl_xor(lm, mask));
    float ep[4]; float ls = 0.f;
    #pragma unroll
    for (int j = 0; j < 4; ++j) { ep[j] = __expf(p[j] - lm); ls += ep[j]; }
    #pragma unroll
    for (int mask = 1; mask <= 8; mask <<= 1)
        ls += __shfl_xor(ls, mask);
    const float invZ = 1.0f / ls;

    float bv = p[0]; int bi = tx * 4;
    #pragma unroll
    for (int j = 1; j < 4; ++j)
        if (p[j] > bv) { bv = p[j]; bi = tx * 4 + j; }
    #pragma unroll
    for (int mask = 1; mask <= 8; mask <<= 1) {
        const float ov = __shfl_xor(bv, mask);
        const int   oi = __shfl_xor(bi, mask);
        if (ov > bv || (ov == bv && oi < bi)) { bv = ov; bi = oi; }
    }
    if (tx == 0) { eidx[s] = bi; gtop[s] = invZ; }

    float colsum[4];
    #pragma unroll
    for (int j = 0; j < 4; ++j) colsum[j] = ep[j] * invZ;
    #pragma unroll
    for (int j = 0; j < 4; ++j) {
        colsum[j] += __shfl_xor(colsum[j], 16);
        colsum[j] += __shfl_xor(colsum[j], 32);
    }
    const int wave = tid >> 6;
    const int lane = tid & 63;
    if (lane < 16) {
        #pragma unroll
        for (int j = 0; j < 4; ++j) cs[wave][lane * 4 + j] = colsum[j];
    }
    __syncthreads();
    if (tid < 64) {
        partial_me[(size_t)blockIdx.x * 64 + tid] =
            cs[0][tid] + cs[1][tid] + cs[2][tid] + cs[3][tid];
    }
}

// ---------------------------------------------------------------------------
// Kernel C: per-expert ordered rank + capacity + scatter + fused l_aux.
// ---------------------------------------------------------------------------
__global__ __launch_bounds__(1024) void rank_scatter_laux(
    const int* __restrict__ eidx, const float* __restrict__ gtop,
    const float* __restrict__ partial_me, float* __restrict__ out)
{
    const int e = blockIdx.x;
    const int tid = threadIdx.x;
    const int wave = tid >> 6;
    const int lane = tid & 63;
    __shared__ int wave_tot[16];
    __shared__ float red[8];

    int ev[8];
    #pragma unroll
    for (int r = 0; r < 8; ++r) ev[r] = eidx[r * 1024 + tid];

    int running = 0;
    #pragma unroll
    for (int r = 0; r < 8; ++r) {
        const bool m = (ev[r] == e);
        const unsigned long long b = __ballot(m);
        if (lane == 0) wave_tot[wave] = __popcll(b);
        __syncthreads();
        int off = running;
        #pragma unroll
        for (int w = 0; w < 16; ++w) if (w < wave) off += wave_tot[w];
        const int rank = off + __popcll(b & ((1ull << lane) - 1ull));
        if (m && rank < TCAP) {
            const int s = r * 1024 + tid;
            const size_t base = 1 + ((size_t)s * TE + e) * TCAP + (size_t)rank;
            out[base] = gtop[s];        // combine_weights
            out[base + SEC] = 1.0f;     // dispatch_mask (as float)
        }
        int tot = 0;
        #pragma unroll
        for (int w = 0; w < 16; ++w) tot += wave_tot[w];
        running += tot;
        __syncthreads();
    }
    if (tid == 0) out[1 + 2 * SEC + e] = (float)running;   // exp_counts

    float v = (tid < 512) ? partial_me[(size_t)tid * 64 + e] : 0.f;
    #pragma unroll
    for (int mask = 32; mask >= 1; mask >>= 1) v += __shfl_xor(v, mask);
    if (lane == 0 && wave < 8) red[wave] = v;
    __syncthreads();
    if (tid == 0) {
        float ms = 0.f;
        #pragma unroll
        for (int w = 0; w < 8; ++w) ms += red[w];
        const float me = ms * (1.0f / TS);
        const float ce = (float)running * (1.0f / TS);
        atomicAdd(out, me * ce * (float)TE);
    }
}

extern "C" void kernel_launch(void* const* d_in, const int* in_sizes, int n_in,
                              void* d_out, int out_size, void* d_ws, size_t ws_size,
                              hipStream_t stream) {
    const float* x  = (const float*)d_in[0];
    const float* wg = (const float*)d_in[1];
    float* out = (float*)d_out;

    // workspace layout
    float* part       = (float*)d_ws;                        // KS*TS*TE floats (33.6 MB)
    int*   eidx       = (int*)(part + (size_t)KS * TS * TE); // TS ints
    float* gtop       = (float*)(eidx + TS);                 // TS floats
    float* partial_me = gtop + TS;                           // 512*64 floats

    hipLaunchKernelGGL(gemm_fill_fused, dim3(1536), dim3(512), 0, stream,
                       x, wg, part, (f32x4*)out, out);
    hipLaunchKernelGGL(softmax_argmax, dim3(512), dim3(256), 0, stream,
                       part, eidx, gtop, partial_me);
    hipLaunchKernelGGL(rank_scatter_laux, dim3(64), dim3(1024), 0, stream,
                       eidx, gtop, partial_me, out);
}

// Round 17
// 145.175 us; speedup vs baseline: 1.1733x; 1.1733x over previous
//
#include <hip/hip_runtime.h>
#include <cstdint>

#define TS 8192      // tokens (S)
#define TD 4096      // model dim (D)
#define TE 64        // experts (E)
#define TCAP 128     // capacity
#define KS 16        // K-splits
#define KB (TD/KS)   // 256 k per block
#define KC 32        // k-chunk staged in LDS
#define TB 256       // tokens per block
#define NTB (TS/TB)  // 32 token-blocks

static constexpr size_t SEC = (size_t)TS * TE * TCAP;  // 67,108,864

typedef float f32x4 __attribute__((ext_vector_type(4)));

// ---------------------------------------------------------------------------
// Kernel A: block-role fused GEMM + fill (R12 optimum restored).
// 2560 blocks x 512 threads.
//  - bid <  512: GEMM role (KS=16, TB=256, 8tok x 4exp, reg-prefetch,
//    268 MB in-wave fill quota = vecs [0, 16,777,216) — proven free).
//  - bid >= 512: 2048 pure-fill blocks x 8192 vecs (128 KB each; finer
//    granularity than R12's 256 KB for smoother backfill as GEMM blocks
//    retire), vecs [16,777,216 , 33,554,432), NT stores, no LDS/barriers.
// ---------------------------------------------------------------------------
__global__ __launch_bounds__(512, 4) void gemm_fill_fused(
    const float* __restrict__ x, const float* __restrict__ wg,
    float* __restrict__ part, f32x4* __restrict__ out4,
    float* __restrict__ out)
{
    __shared__ float xs[KC][260];   // [k][token]
    __shared__ float wsh[KC][68];   // [k][expert]

    const int tid = threadIdx.x;
    const int bid = blockIdx.x;
    const f32x4 z4 = {0.f, 0.f, 0.f, 0.f};

    if (bid >= 512) {
        // ---------------- fill role: decoupled pure-write blocks ----------
        const int fid = bid - 512;              // 0..2047
        const long base = 16777216L + (long)fid * 8192;
        #pragma unroll
        for (int j = 0; j < 16; ++j)
            __builtin_nontemporal_store(z4, &out4[base + (long)j * 512 + tid]);
        if (fid == 0) {
            if (tid < 16)                        // floats [2*SEC , 2*SEC+64)
                __builtin_nontemporal_store(z4, &out4[33554432L + tid]);
            if (tid == 16) out[2 * SEC + 64] = 0.f;
        }
        return;
    }

    // ---------------- GEMM role -------------------------------------------
    const int tb  = bid & (NTB - 1);
    const int ks  = bid >> 5;       // 0..15
    const int tok0 = tb * TB;
    const int tx = tid & 15;        // experts tx*4..+3
    const int ty = tid >> 4;        // tokens ty*8..+7
    const int kq_s  = tid & 7;
    const int row_s = tid >> 3;
    const long fill0 = (long)bid * 32768;   // 512 x 32768 vecs = 268 MB

    float acc[8][4];
    #pragma unroll
    for (int i = 0; i < 8; ++i)
        #pragma unroll
        for (int j = 0; j < 4; ++j) acc[i][j] = 0.f;

    // prefetch iteration 0 into registers
    f32x4 rx[4], rw;
    {
        const int k0 = ks * KB;
        #pragma unroll
        for (int r = 0; r < 4; ++r)
            rx[r] = __builtin_nontemporal_load(reinterpret_cast<const f32x4*>(
                &x[(size_t)(tok0 + r * 64 + row_s) * TD + k0 + kq_s * 4]));
        rw = *reinterpret_cast<const f32x4*>(&wg[(size_t)row_s * TD + k0 + kq_s * 4]);
    }

    for (int it = 0; it < KB / KC; ++it) {   // 8 iterations
        // commit staged registers to LDS (transposed)
        #pragma unroll
        for (int r = 0; r < 4; ++r) {
            const int t = r * 64 + row_s;
            xs[kq_s*4+0][t] = rx[r].x; xs[kq_s*4+1][t] = rx[r].y;
            xs[kq_s*4+2][t] = rx[r].z; xs[kq_s*4+3][t] = rx[r].w;
        }
        wsh[kq_s*4+0][row_s] = rw.x; wsh[kq_s*4+1][row_s] = rw.y;
        wsh[kq_s*4+2][row_s] = rw.z; wsh[kq_s*4+3][row_s] = rw.w;
        __syncthreads();
        // prefetch next iteration (drained during FMA section)
        if (it + 1 < KB / KC) {
            const int k0 = ks * KB + (it + 1) * KC;
            #pragma unroll
            for (int r = 0; r < 4; ++r)
                rx[r] = __builtin_nontemporal_load(reinterpret_cast<const f32x4*>(
                    &x[(size_t)(tok0 + r * 64 + row_s) * TD + k0 + kq_s * 4]));
            rw = *reinterpret_cast<const f32x4*>(&wg[(size_t)row_s * TD + k0 + kq_s * 4]);
        }
        // FMA section; 8 fill stores front-loaded at k=0..7
        #pragma unroll
        for (int k = 0; k < KC; ++k) {
            if (k < 8) {
                __builtin_nontemporal_store(z4,
                    &out4[fill0 + (long)it * 4096 + k * 512 + tid]);
            }
            const f32x4 a0 = *reinterpret_cast<const f32x4*>(&xs[k][ty * 8]);
            const f32x4 a1 = *reinterpret_cast<const f32x4*>(&xs[k][ty * 8 + 4]);
            const f32x4 b  = *reinterpret_cast<const f32x4*>(&wsh[k][tx * 4]);
            acc[0][0] = fmaf(a0.x, b.x, acc[0][0]);
            acc[0][1] = fmaf(a0.x, b.y, acc[0][1]);
            acc[0][2] = fmaf(a0.x, b.z, acc[0][2]);
            acc[0][3] = fmaf(a0.x, b.w, acc[0][3]);
            acc[1][0] = fmaf(a0.y, b.x, acc[1][0]);
            acc[1][1] = fmaf(a0.y, b.y, acc[1][1]);
            acc[1][2] = fmaf(a0.y, b.z, acc[1][2]);
            acc[1][3] = fmaf(a0.y, b.w, acc[1][3]);
            acc[2][0] = fmaf(a0.z, b.x, acc[2][0]);
            acc[2][1] = fmaf(a0.z, b.y, acc[2][1]);
            acc[2][2] = fmaf(a0.z, b.z, acc[2][2]);
            acc[2][3] = fmaf(a0.z, b.w, acc[2][3]);
            acc[3][0] = fmaf(a0.w, b.x, acc[3][0]);
            acc[3][1] = fmaf(a0.w, b.y, acc[3][1]);
            acc[3][2] = fmaf(a0.w, b.z, acc[3][2]);
            acc[3][3] = fmaf(a0.w, b.w, acc[3][3]);
            acc[4][0] = fmaf(a1.x, b.x, acc[4][0]);
            acc[4][1] = fmaf(a1.x, b.y, acc[4][1]);
            acc[4][2] = fmaf(a1.x, b.z, acc[4][2]);
            acc[4][3] = fmaf(a1.x, b.w, acc[4][3]);
            acc[5][0] = fmaf(a1.y, b.x, acc[5][0]);
            acc[5][1] = fmaf(a1.y, b.y, acc[5][1]);
            acc[5][2] = fmaf(a1.y, b.z, acc[5][2]);
            acc[5][3] = fmaf(a1.y, b.w, acc[5][3]);
            acc[6][0] = fmaf(a1.z, b.x, acc[6][0]);
            acc[6][1] = fmaf(a1.z, b.y, acc[6][1]);
            acc[6][2] = fmaf(a1.z, b.z, acc[6][2]);
            acc[6][3] = fmaf(a1.z, b.w, acc[6][3]);
            acc[7][0] = fmaf(a1.w, b.x, acc[7][0]);
            acc[7][1] = fmaf(a1.w, b.y, acc[7][1]);
            acc[7][2] = fmaf(a1.w, b.z, acc[7][2]);
            acc[7][3] = fmaf(a1.w, b.w, acc[7][3]);
        }
        __syncthreads();
    }
    // write partial logits: part[ks][tok][exp]
    #pragma unroll
    for (int i = 0; i < 8; ++i) {
        const int t = tok0 + ty * 8 + i;
        f32x4 v;
        v.x = acc[i][0]; v.y = acc[i][1]; v.z = acc[i][2]; v.w = acc[i][3];
        *reinterpret_cast<f32x4*>(&part[((size_t)ks * TS + t) * TE + tx * 4]) = v;
    }
}

// ---------------------------------------------------------------------------
// Kernel B: reduce K-split partials + softmax + argmax per token.
// ---------------------------------------------------------------------------
__global__ __launch_bounds__(256) void softmax_argmax(
    const float* __restrict__ part, int* __restrict__ eidx,
    float* __restrict__ gtop, float* __restrict__ partial_me)
{
    __shared__ float cs[4][64];
    const int tid = threadIdx.x;
    const int tx = tid & 15;
    const int ty = tid >> 4;
    const int s = blockIdx.x * 16 + ty;

    float p[4] = {0.f, 0.f, 0.f, 0.f};
    #pragma unroll
    for (int ks = 0; ks < KS; ++ks) {
        const f32x4 v = *reinterpret_cast<const f32x4*>(
            &part[((size_t)ks * TS + s) * TE + tx * 4]);
        p[0] += v.x; p[1] += v.y; p[2] += v.z; p[3] += v.w;
    }

    float lm = fmaxf(fmaxf(p[0], p[1]), fmaxf(p[2], p[3]));
    #pragma unroll
    for (int mask = 1; mask <= 8; mask <<= 1)
        lm = fmaxf(lm, __shfl_xor(lm, mask));
    float ep[4]; float ls = 0.f;
    #pragma unroll
    for (int j = 0; j < 4; ++j) { ep[j] = __expf(p[j] - lm); ls += ep[j]; }
    #pragma unroll
    for (int mask = 1; mask <= 8; mask <<= 1)
        ls += __shfl_xor(ls, mask);
    const float invZ = 1.0f / ls;

    float bv = p[0]; int bi = tx * 4;
    #pragma unroll
    for (int j = 1; j < 4; ++j)
        if (p[j] > bv) { bv = p[j]; bi = tx * 4 + j; }
    #pragma unroll
    for (int mask = 1; mask <= 8; mask <<= 1) {
        const float ov = __shfl_xor(bv, mask);
        const int   oi = __shfl_xor(bi, mask);
        if (ov > bv || (ov == bv && oi < bi)) { bv = ov; bi = oi; }
    }
    if (tx == 0) { eidx[s] = bi; gtop[s] = invZ; }

    float colsum[4];
    #pragma unroll
    for (int j = 0; j < 4; ++j) colsum[j] = ep[j] * invZ;
    #pragma unroll
    for (int j = 0; j < 4; ++j) {
        colsum[j] += __shfl_xor(colsum[j], 16);
        colsum[j] += __shfl_xor(colsum[j], 32);
    }
    const int wave = tid >> 6;
    const int lane = tid & 63;
    if (lane < 16) {
        #pragma unroll
        for (int j = 0; j < 4; ++j) cs[wave][lane * 4 + j] = colsum[j];
    }
    __syncthreads();
    if (tid < 64) {
        partial_me[(size_t)blockIdx.x * 64 + tid] =
            cs[0][tid] + cs[1][tid] + cs[2][tid] + cs[3][tid];
    }
}

// ---------------------------------------------------------------------------
// Kernel C: per-expert ordered rank + capacity + scatter + fused l_aux.
// ---------------------------------------------------------------------------
__global__ __launch_bounds__(1024) void rank_scatter_laux(
    const int* __restrict__ eidx, const float* __restrict__ gtop,
    const float* __restrict__ partial_me, float* __restrict__ out)
{
    const int e = blockIdx.x;
    const int tid = threadIdx.x;
    const int wave = tid >> 6;
    const int lane = tid & 63;
    __shared__ int wave_tot[16];
    __shared__ float red[8];

    int ev[8];
    #pragma unroll
    for (int r = 0; r < 8; ++r) ev[r] = eidx[r * 1024 + tid];

    int running = 0;
    #pragma unroll
    for (int r = 0; r < 8; ++r) {
        const bool m = (ev[r] == e);
        const unsigned long long b = __ballot(m);
        if (lane == 0) wave_tot[wave] = __popcll(b);
        __syncthreads();
        int off = running;
        #pragma unroll
        for (int w = 0; w < 16; ++w) if (w < wave) off += wave_tot[w];
        const int rank = off + __popcll(b & ((1ull << lane) - 1ull));
        if (m && rank < TCAP) {
            const int s = r * 1024 + tid;
            const size_t base = 1 + ((size_t)s * TE + e) * TCAP + (size_t)rank;
            out[base] = gtop[s];        // combine_weights
            out[base + SEC] = 1.0f;     // dispatch_mask (as float)
        }
        int tot = 0;
        #pragma unroll
        for (int w = 0; w < 16; ++w) tot += wave_tot[w];
        running += tot;
        __syncthreads();
    }
    if (tid == 0) out[1 + 2 * SEC + e] = (float)running;   // exp_counts

    float v = (tid < 512) ? partial_me[(size_t)tid * 64 + e] : 0.f;
    #pragma unroll
    for (int mask = 32; mask >= 1; mask >>= 1) v += __shfl_xor(v, mask);
    if (lane == 0 && wave < 8) red[wave] = v;
    __syncthreads();
    if (tid == 0) {
        float ms = 0.f;
        #pragma unroll
        for (int w = 0; w < 8; ++w) ms += red[w];
        const float me = ms * (1.0f / TS);
        const float ce = (float)running * (1.0f / TS);
        atomicAdd(out, me * ce * (float)TE);
    }
}

extern "C" void kernel_launch(void* const* d_in, const int* in_sizes, int n_in,
                              void* d_out, int out_size, void* d_ws, size_t ws_size,
                              hipStream_t stream) {
    const float* x  = (const float*)d_in[0];
    const float* wg = (const float*)d_in[1];
    float* out = (float*)d_out;

    // workspace layout
    float* part       = (float*)d_ws;                        // KS*TS*TE floats (33.6 MB)
    int*   eidx       = (int*)(part + (size_t)KS * TS * TE); // TS ints
    float* gtop       = (float*)(eidx + TS);                 // TS floats
    float* partial_me = gtop + TS;                           // 512*64 floats

    hipLaunchKernelGGL(gemm_fill_fused, dim3(2560), dim3(512), 0, stream,
                       x, wg, part, (f32x4*)out, out);
    hipLaunchKernelGGL(softmax_argmax, dim3(512), dim3(256), 0, stream,
                       part, eidx, gtop, partial_me);
    hipLaunchKernelGGL(rank_scatter_laux, dim3(64), dim3(1024), 0, stream,
                       eidx, gtop, partial_me, out);
}